// Round 15
// baseline (262.210 us; speedup 1.0000x reference)
//
#include <hip/hip_runtime.h>
#include <hip/hip_fp16.h>
#include <hip/hip_cooperative_groups.h>

namespace cg = cooperative_groups;

// GCN 2-layer forward on MI355X — R25: R24 + cooperative fused k_csr
// (hist+scatter). Phase 1: per-tile LDS histogram (one col pass) flushed to
// global bucketCnt. grid.sync(). Phase 2: the SAME LDS histogram (persists
// across the sync) feeds the local offsets; local bucketCnt scan + chunk
// claim + staged scatter as in R24. col passes 3 -> 2; one dispatch+gap
// deleted. 196 blocks <= 256 CUs => co-residency safe.
// Kept from R24: 256-B aligned workspace (h1 row-gather alignment!), MFMA
// GEMM1+GEMM2 (hi/lo fp16), W2TS=68 bank floor, GP=40 packed g, LDS pairs
// staging in k_bucket, rowptr/deg preload, act-guarded agg2, index
// prefetch, x8-padded esrc + tail guard, unroll-1 pins.
// Note: ~43us of measured time is the harness's 256MiB workspace re-poison
// fill (outside kernel control).
// Pipeline: wprep(+zero+sentinels) -> csr(coop) -> bucket(deg) -> gemm1m ->
//           agg1mm -> agg2
// d_in: [0]=x (N*128 f32), [1]=edge_index (2*E i32), [2]=W1 (128*64),
//       [3]=b1 (64), [4]=W2 (64*40), [5]=b2 (40)
// d_out: N*40 f32

#define FIN 128
#define H1  64
#define C2  40
#define GP  40            // packed row stride (halves) for g => 80 B rows
#define TILE 8192         // edges per csr tile
#define BCAP 7168         // padded bucket capacity (mean 4096 + <=1792 pad)
#define STAGE_CAP 4608    // LDS pairs-staging capacity (mean 4092 + 8 sigma)
#define WTS 132           // padded W1t row stride (halves): bank-conflict-free
#define W2TS 68           // padded W2t/hs row stride (halves): 34-dword => bank floor

typedef _Float16 half4_t __attribute__((ext_vector_type(4)));
typedef float float4_t __attribute__((ext_vector_type(4)));

// ---------- W1/W2 planes; zero bucketCnt+goff; sentinel rows ----------
__global__ __launch_bounds__(256) void k_wprep(const float* __restrict__ W1,
                                               _Float16* __restrict__ W1th,
                                               _Float16* __restrict__ W1tl,
                                               const float* __restrict__ W2,
                                               _Float16* __restrict__ W2th,
                                               _Float16* __restrict__ W2tl,
                                               int* __restrict__ bucketCnt,
                                               int* __restrict__ goff,
                                               __half* __restrict__ h1,
                                               __half* __restrict__ g,
                                               int NB, int N) {
    int idx = blockIdx.x * 256 + threadIdx.x;
    if (idx < NB) { bucketCnt[idx] = 0; goff[idx] = 0; }
    if (idx < FIN * H1) {
        // W1 [k][o] -> planes [o][WTS]; consecutive idx = consecutive o (coalesced read)
        int k = idx >> 6, o = idx & 63;
        float wv = W1[k * H1 + o];
        _Float16 hi = (_Float16)wv;
        W1th[o * WTS + k] = hi;
        W1tl[o * WTS + k] = (_Float16)(wv - (float)hi);
    } else if (idx < FIN * H1 + 48 * 64) {
        // W2 [k][c] -> planes [n][W2TS], n<48 (cols 40-47 zero); coalesced over n
        int i = idx - FIN * H1;
        int kk = i / 48, n = i % 48;
        float wv = (n < C2) ? W2[kk * C2 + n] : 0.f;
        _Float16 hi = (_Float16)wv;
        W2th[n * W2TS + kk] = hi;
        W2tl[n * W2TS + kk] = (_Float16)(wv - (float)hi);
    } else if (idx < FIN * H1 + 48 * 64 + 32) {
        // sentinel row h1[N] (64 halves = 32 uints): pad entries src==N -> 0
        ((unsigned*)(h1 + (size_t)N * H1))[idx - (FIN * H1 + 48 * 64)] = 0u;
    } else if (idx < FIN * H1 + 48 * 64 + 52) {
        // sentinel row g[N] (40 halves = 20 uints)
        ((unsigned*)(g + (size_t)N * GP))[idx - (FIN * H1 + 48 * 64 + 32)] = 0u;
    }
}

// ---------- cooperative fused histogram + scatter ----------
// Phase 1: per-tile LDS histogram (lcnt) from one col pass; flush to global
// bucketCnt. grid.sync(). Phase 2: lcnt persists — local scan of final
// bucketCnt for bases, lex scan of lcnt for tile-local offsets, chunk claim
// via goff, staged sort, coalesced pairs write.
// packed pair: bits 0..23 = src row, bits 24..31 = dest low 8.
__global__ __launch_bounds__(512) void k_csr(const int* __restrict__ row,
                                             const int* __restrict__ col,
                                             int* __restrict__ bucketCnt,
                                             int* __restrict__ goff,
                                             int* __restrict__ pairs,
                                             int E, int NB) {
    __shared__ int2 stage[TILE];         // 64 KB
    __shared__ int lcnt[512];
    __shared__ int lex[512];
    __shared__ int gbase[512];
    __shared__ int scs[512];
    int t = threadIdx.x, tile = blockIdx.x;
    int base = tile * TILE;
    int cnt = min(TILE, E - base);

    // ---- phase 1: tile histogram + global flush ----
    lcnt[t] = 0;
    __syncthreads();
    for (int i = t; i < cnt; i += 512) atomicAdd(&lcnt[col[base + i] >> 8], 1);
    __syncthreads();
    if (t < NB && lcnt[t]) atomicAdd(&bucketCnt[t], lcnt[t]);

    cg::this_grid().sync();              // all tiles' counts now in bucketCnt

    // ---- phase 2: bases + scatter (lcnt kept from phase 1) ----
    int bc = (t < NB) ? bucketCnt[t] : 0;
    scs[t] = bc;
    __syncthreads();
    for (int off = 1; off < 512; off <<= 1) {
        int u = (t >= off) ? scs[t - off] : 0;
        __syncthreads();
        scs[t] += u;
        __syncthreads();
    }
    int rex = scs[t] - bc;               // exclusive bucket base

    int myc = lcnt[t];
    lex[t] = myc;
    __syncthreads();
    for (int off = 1; off < 512; off <<= 1) {
        int u = (t >= off) ? lex[t - off] : 0;
        __syncthreads();
        lex[t] += u;
        __syncthreads();
    }
    int ex = lex[t] - myc;
    __syncthreads();
    lex[t] = ex;
    lcnt[t] = ex;                         // local cursor
    if (t < NB && myc > 0) gbase[t] = rex + atomicAdd(&goff[t], myc);
    __syncthreads();

    for (int i = t; i < cnt; i += 512) {
        int r = row[base + i], c = col[base + i];
        int lpos = atomicAdd(&lcnt[c >> 8], 1);
        stage[lpos] = make_int2(r, c);
    }
    __syncthreads();

    for (int i = t; i < cnt; i += 512) {
        int2 p = stage[i];
        int b = p.y >> 8;
        pairs[gbase[b] + (i - lex[b])] = p.x | ((p.y & 255) << 24);
    }
}

// ---------- per-bucket sort by dest; LDS pairs staging; local base scans ----------
__global__ __launch_bounds__(512) void k_bucket(const int* __restrict__ pairs,
                                                const int* __restrict__ bucketCnt,
                                                int* __restrict__ rowptr,
                                                int* __restrict__ deg,
                                                int* __restrict__ esrc,
                                                int N, int NB) {
    __shared__ int dcnt[256];
    __shared__ int sr[256], sp[256];
    __shared__ int cur[256];
    __shared__ int bsc[512], bsp[512];   // bucket-level scans (raw, padded)
    __shared__ int sb[4];
    __shared__ int outbuf[BCAP];         // 28 KB
    __shared__ int pstage[STAGE_CAP];    // 18 KB: this bucket's pairs
    int t = threadIdx.x, b = blockIdx.x;
    int d0 = b << 8;
    int nd = min(256, N - d0);

    // local scans over bucketCnt: bstart = rawEx[b], pstart = padEx[b]
    int c0 = (t < NB) ? bucketCnt[t] : 0;
    int p0 = (t < NB) ? (((c0 + 7) & ~7) + 2048) : 0;
    bsc[t] = c0; bsp[t] = p0;
    __syncthreads();
    for (int off = 1; off < 512; off <<= 1) {
        int a = (t >= off) ? bsc[t - off] : 0;
        int bb = (t >= off) ? bsp[t - off] : 0;
        __syncthreads();
        bsc[t] += a; bsp[t] += bb;
        __syncthreads();
    }
    if (t == b) { sb[0] = bsc[b] - c0; sb[1] = c0; sb[2] = bsp[b] - p0; }
    __syncthreads();
    int bstart = sb[0];
    int cnt = sb[1];
    int pstart = sb[2];

    // stage this bucket's pairs in LDS (one coalesced global read)
    bool staged = (cnt <= STAGE_CAP);
    if (staged) {
        for (int i = t; i < cnt; i += 512) pstage[i] = pairs[bstart + i];
    }
    if (t < 256) dcnt[t] = 0;
    __syncthreads();
    for (int i = t; i < cnt; i += 512) {
        unsigned p = (unsigned)(staged ? pstage[i] : pairs[bstart + i]);
        atomicAdd(&dcnt[p >> 24], 1);
    }
    __syncthreads();

    int myc = 0, myp = 0;
    if (t < 256) {
        myc = dcnt[t];
        myp = (myc + 7) & ~7;
        sr[t] = myc; sp[t] = myp;
    }
    __syncthreads();
    for (int off = 1; off < 256; off <<= 1) {
        int a = 0, c2 = 0;
        if (t < 256 && t >= off) { a = sr[t - off]; c2 = sp[t - off]; }
        __syncthreads();
        if (t < 256) { sr[t] += a; sp[t] += c2; }
        __syncthreads();
    }
    if (t < 256) {
        int pex = sp[t] - myp;
        cur[t] = pex;
        if (t < nd) {
            rowptr[d0 + t] = pstart + pex;
            deg[d0 + t] = myc;            // degree for free
        }
    }
    __syncthreads();
    int pcnt = sp[255];

    if (pcnt <= BCAP) {
        for (int i = t; i < cnt; i += 512) {
            unsigned p = (unsigned)(staged ? pstage[i] : pairs[bstart + i]);
            int lpos = atomicAdd(&cur[p >> 24], 1);
            outbuf[lpos] = (int)(p & 0xFFFFFF);
        }
        __syncthreads();
        if (t < 256) {
            int pex = sp[t] - myp;
            for (int j = myc; j < myp; ++j) outbuf[pex + j] = N;   // sentinel pad
        }
        __syncthreads();
        for (int i = t; i < pcnt; i += 512) esrc[pstart + i] = outbuf[i];
    } else {
        for (int i = t; i < cnt; i += 512) {
            unsigned p = (unsigned)(staged ? pstage[i] : pairs[bstart + i]);
            int lpos = atomicAdd(&cur[p >> 24], 1);
            esrc[pstart + lpos] = (int)(p & 0xFFFFFF);
        }
        __syncthreads();
        if (t < 256) {
            int pex = sp[t] - myp;
            for (int j = myc; j < myp; ++j) esrc[pstart + pex + j] = N;
        }
    }
}

// ---------- GEMM1 via MFMA: h1' = (x@W1)*dinv, hi/lo fp16 split ----------
__global__ __launch_bounds__(256) void k_gemm1m(const float* __restrict__ x,
                                                const _Float16* __restrict__ W1th,
                                                const _Float16* __restrict__ W1tl,
                                                const int* __restrict__ deg,
                                                __half* __restrict__ h1, int N) {
    __shared__ alignas(16) _Float16 Wh[H1 * WTS];   // 16.5 KB
    __shared__ alignas(16) _Float16 Wl[H1 * WTS];   // 16.5 KB
    int t = threadIdx.x;

    {   // stage both planes: 8448 halves = 1056 uint4 each
        const uint4* sh = (const uint4*)W1th;
        const uint4* sl = (const uint4*)W1tl;
        uint4* dh = (uint4*)Wh;
        uint4* dl = (uint4*)Wl;
        for (int i = t; i < (H1 * WTS) / 8; i += 256) { dh[i] = sh[i]; dl[i] = sl[i]; }
    }

    int wv = t >> 6, l = t & 63;
    int col = l & 15;             // node within 16-tile (A-row lane index)
    int krow = l >> 4;            // 0..3
    int node = blockIdx.x * 64 + wv * 16 + col;
    int nodec = min(node, N - 1);

    // B fragments from x: lane holds x[node][kt*16 + krow*4 + 0..3]
    half4_t bh[8], bl[8];
    const float4* xr = (const float4*)(x + (size_t)nodec * FIN);
#pragma unroll
    for (int kt = 0; kt < 8; ++kt) {
        float4 v = xr[kt * 4 + krow];
        half4_t hi, lo;
        hi[0] = (_Float16)v.x; lo[0] = (_Float16)(v.x - (float)hi[0]);
        hi[1] = (_Float16)v.y; lo[1] = (_Float16)(v.y - (float)hi[1]);
        hi[2] = (_Float16)v.z; lo[2] = (_Float16)(v.z - (float)hi[2]);
        hi[3] = (_Float16)v.w; lo[3] = (_Float16)(v.w - (float)hi[3]);
        bh[kt] = hi; bl[kt] = lo;
    }
    float dcv = rsqrtf((float)deg[nodec] + 1.0f);
    __syncthreads();

    float4_t acc[4];
#pragma unroll
    for (int ot = 0; ot < 4; ++ot) acc[ot] = (float4_t){0.f, 0.f, 0.f, 0.f};

#pragma unroll
    for (int kt = 0; kt < 8; ++kt) {
#pragma unroll
        for (int ot = 0; ot < 4; ++ot) {
            int aoff = ((ot * 16 + col) * WTS + kt * 16 + krow * 4) >> 2;  // half4 units
            half4_t ah = ((const half4_t*)Wh)[aoff];
            half4_t al = ((const half4_t*)Wl)[aoff];
            acc[ot] = __builtin_amdgcn_mfma_f32_16x16x16f16(ah, bh[kt], acc[ot], 0, 0, 0);
            acc[ot] = __builtin_amdgcn_mfma_f32_16x16x16f16(ah, bl[kt], acc[ot], 0, 0, 0);
            acc[ot] = __builtin_amdgcn_mfma_f32_16x16x16f16(al, bh[kt], acc[ot], 0, 0, 0);
        }
    }

    if (node < N) {
#pragma unroll
        for (int ot = 0; ot < 4; ++ot) {
            union { __half h[4]; uint2 u; } pk;
#pragma unroll
            for (int r = 0; r < 4; ++r) pk.h[r] = __float2half_rn(acc[ot][r] * dcv);
            *(uint2*)&h1[(size_t)node * H1 + ot * 16 + krow * 4] = pk.u;
        }
    }
}

// ---------- fused agg1 + bias + ReLU + GEMM2(MFMA) per 64-node block ----------
// 512 threads = 8 waves. Aggregation: R17 shape + index prefetch; rowptr/deg
// preloaded into LDS. Epilogue: hs hi/lo planes (W2TS=68 bank floor).
// GEMM2: 12 16x16 MFMA tiles / 8 waves, 3 mfma/k-step.
__global__ __launch_bounds__(512) void k_agg1mm(const int* __restrict__ rowptr,
                                                const int* __restrict__ deg,
                                                const int* __restrict__ esrc,
                                                const __half* __restrict__ h1,
                                                const float* __restrict__ b1,
                                                const _Float16* __restrict__ W2th,
                                                const _Float16* __restrict__ W2tl,
                                                __half* __restrict__ g, int N) {
    __shared__ alignas(16) _Float16 hsh[64][W2TS];   // 8.7 KB
    __shared__ alignas(16) _Float16 hsl[64][W2TS];   // 8.7 KB
    __shared__ alignas(16) _Float16 Wth[48][W2TS];   // 6.5 KB
    __shared__ alignas(16) _Float16 Wtl[48][W2TS];   // 6.5 KB
    __shared__ float sdc[64];
    __shared__ int srp[64], sdg[64];
    int t = threadIdx.x;
    int node0 = blockIdx.x * 64;

    {   // stage W2t planes: 408 uint4 each
        const uint4* sh = (const uint4*)W2th;
        const uint4* sl = (const uint4*)W2tl;
        uint4* dh = (uint4*)Wth;
        uint4* dl = (uint4*)Wtl;
        for (int i = t; i < (48 * W2TS) / 8; i += 512) { dh[i] = sh[i]; dl[i] = sl[i]; }
    }
    if (t < 64) {   // coalesced rowptr/deg preload for the block's nodes
        int node = node0 + t;
        srp[t] = (node < N) ? rowptr[node] : 0;
        sdg[t] = (node < N) ? deg[node] : 0;
    }
    __syncthreads();

    int wv = t >> 6, lane = t & 63;
    int half = lane >> 5;                // edge-octet selector
    int f = lane & 31;                   // feature-pair index
    float2 b1v = *(const float2*)&b1[2 * f];
    const __half2* hp = (const __half2*)h1;

    // aggregation: 8 nodes per wave, sequential (R17 loop + index prefetch)
#pragma unroll 1
    for (int j = 0; j < 8; ++j) {
        int r = wv * 8 + j;
        int node = node0 + r;
        if (node >= N) {
            if (lane < 32) { *(unsigned*)&hsh[r][2 * f] = 0u; *(unsigned*)&hsl[r][2 * f] = 0u; }
            if (lane == 0) sdc[r] = 0.f;
            continue;
        }
        int start = srp[r], d = sdg[r];
        int d8 = (d + 7) & ~7;
        float dc = rsqrtf((float)d + 1.0f);
        float ax = 0.f, ay = 0.f;
        int i = 0;
        // prime: first iteration's indices (over-read past segment is safe)
        int4 sA = *(const int4*)&esrc[start + half * 8];
        int4 sB = *(const int4*)&esrc[start + half * 8 + 4];
#pragma unroll 1
        for (; i + 16 <= d8; i += 16) {
            int4 cA = sA, cB = sB;
            int nb = start + i + 16 + half * 8;
            sA = *(const int4*)&esrc[nb];        // next-iter indices in flight
            sB = *(const int4*)&esrc[nb + 4];    // under current gathers
            float2 v0 = __half22float2(hp[cA.x * 32 + f]);
            float2 v1 = __half22float2(hp[cA.y * 32 + f]);
            float2 v2 = __half22float2(hp[cA.z * 32 + f]);
            float2 v3 = __half22float2(hp[cA.w * 32 + f]);
            float2 v4 = __half22float2(hp[cB.x * 32 + f]);
            float2 v5 = __half22float2(hp[cB.y * 32 + f]);
            float2 v6 = __half22float2(hp[cB.z * 32 + f]);
            float2 v7 = __half22float2(hp[cB.w * 32 + f]);
            ax += ((v0.x + v1.x) + (v2.x + v3.x)) + ((v4.x + v5.x) + (v6.x + v7.x));
            ay += ((v0.y + v1.y) + (v2.y + v3.y)) + ((v4.y + v5.y) + (v6.y + v7.y));
        }
        if (i < d8) {                    // one 8-edge chunk: 4 per half
            int4 s = *(const int4*)&esrc[start + i + half * 4];
            float2 v0 = __half22float2(hp[s.x * 32 + f]);
            float2 v1 = __half22float2(hp[s.y * 32 + f]);
            float2 v2 = __half22float2(hp[s.z * 32 + f]);
            float2 v3 = __half22float2(hp[s.w * 32 + f]);
            ax += (v0.x + v1.x) + (v2.x + v3.x);
            ay += (v0.y + v1.y) + (v2.y + v3.y);
        }
        // cross-half reduce (both halves end with full sum)
        ax += __shfl(ax, lane ^ 32);
        ay += __shfl(ay, lane ^ 32);
        // self-loop (h1' already has one dinv factor) + bias + ReLU
        float2 sv = __half22float2(hp[node * 32 + f]);
        ax = fmaxf(fmaf(dc, ax + sv.x, b1v.x), 0.f);
        ay = fmaxf(fmaf(dc, ay + sv.y, b1v.y), 0.f);
        if (lane < 32) {
            // hi/lo fp16 split (exact): hs = hi + lo to ~2^-22
            _Float16 axh = (_Float16)ax;
            _Float16 ayh = (_Float16)ay;
            _Float16 axl = (_Float16)(ax - (float)axh);
            _Float16 ayl = (_Float16)(ay - (float)ayh);
            union { _Float16 h[2]; unsigned u; } ph, pl;
            ph.h[0] = axh; ph.h[1] = ayh;
            pl.h[0] = axl; pl.h[1] = ayl;
            *(unsigned*)&hsh[r][2 * f] = ph.u;
            *(unsigned*)&hsl[r][2 * f] = pl.u;
        }
        if (lane == 0) sdc[r] = dc;
    }
    __syncthreads();

    // GEMM2 via MFMA: D[64 nodes][48 cols] = hs(h/l) x W2t(h/l); 12 tiles / 8 waves.
    int l15 = lane & 15, kg = (lane >> 4) * 4;
#pragma unroll 1
    for (int tile = wv; tile < 12; tile += 8) {
        int mt = tile & 3, nt = tile >> 2;
        int arow = mt * 16 + l15;
        int bcol = nt * 16 + l15;
        float4_t acc = (float4_t){0.f, 0.f, 0.f, 0.f};
#pragma unroll
        for (int kt = 0; kt < 4; ++kt) {
            int ko = kt * 16 + kg;
            half4_t ah = *(const half4_t*)&hsh[arow][ko];
            half4_t al = *(const half4_t*)&hsl[arow][ko];
            half4_t bh = *(const half4_t*)&Wth[bcol][ko];
            half4_t bl = *(const half4_t*)&Wtl[bcol][ko];
            acc = __builtin_amdgcn_mfma_f32_16x16x16f16(ah, bh, acc, 0, 0, 0);
            acc = __builtin_amdgcn_mfma_f32_16x16x16f16(ah, bl, acc, 0, 0, 0);
            acc = __builtin_amdgcn_mfma_f32_16x16x16f16(al, bh, acc, 0, 0, 0);
        }
        int colo = nt * 16 + l15;
        if (colo < C2) {                 // cols 40-47 are zero; only <40 stored
#pragma unroll
            for (int r2 = 0; r2 < 4; ++r2) {
                int nd = mt * 16 + (lane >> 4) * 4 + r2;
                int node = node0 + nd;
                if (node < N) {
                    g[(size_t)node * GP + colo] = __float2half_rn(acc[r2] * sdc[nd]);
                }
            }
        }
    }
}

// ---------- agg2: wave per node, packed g rows, act-guarded + prefetch ----------
__global__ __launch_bounds__(256) void k_agg2(const int* __restrict__ rowptr,
                                              const int* __restrict__ deg,
                                              const int* __restrict__ esrc,
                                              const __half* __restrict__ g,
                                              const float* __restrict__ b2,
                                              float* __restrict__ out, int N) {
    int w = (int)((blockIdx.x * blockDim.x + threadIdx.x) >> 6);
    int lane = threadIdx.x & 63;
    if (w >= N) return;
    int half = lane >> 5;
    int f = lane & 31;                   // feature-pair; active f<20
    bool act = f < 20;
    const __half2* gp = (const __half2*)g;  // row stride 20 half2 (80 B)

    int start = rowptr[w], d = deg[w];
    int d8 = (d + 7) & ~7;
    float dc = rsqrtf((float)d + 1.0f);
    float ax = 0.f, ay = 0.f;
    if (act) {                           // f>=20 lanes: no gathers (saved 37.5%)
        int i = 0;
        int4 sA = *(const int4*)&esrc[start + half * 8];
        int4 sB = *(const int4*)&esrc[start + half * 8 + 4];
#pragma unroll 1
        for (; i + 16 <= d8; i += 16) {
            int4 cA = sA, cB = sB;
            int nb = start + i + 16 + half * 8;
            sA = *(const int4*)&esrc[nb];
            sB = *(const int4*)&esrc[nb + 4];
            float2 v0 = __half22float2(gp[cA.x * 20 + f]);
            float2 v1 = __half22float2(gp[cA.y * 20 + f]);
            float2 v2 = __half22float2(gp[cA.z * 20 + f]);
            float2 v3 = __half22float2(gp[cA.w * 20 + f]);
            float2 v4 = __half22float2(gp[cB.x * 20 + f]);
            float2 v5 = __half22float2(gp[cB.y * 20 + f]);
            float2 v6 = __half22float2(gp[cB.z * 20 + f]);
            float2 v7 = __half22float2(gp[cB.w * 20 + f]);
            ax += ((v0.x + v1.x) + (v2.x + v3.x)) + ((v4.x + v5.x) + (v6.x + v7.x));
            ay += ((v0.y + v1.y) + (v2.y + v3.y)) + ((v4.y + v5.y) + (v6.y + v7.y));
        }
        if (i < d8) {
            int4 s = *(const int4*)&esrc[start + i + half * 4];
            float2 v0 = __half22float2(gp[s.x * 20 + f]);
            float2 v1 = __half22float2(gp[s.y * 20 + f]);
            float2 v2 = __half22float2(gp[s.z * 20 + f]);
            float2 v3 = __half22float2(gp[s.w * 20 + f]);
            ax += (v0.x + v1.x) + (v2.x + v3.x);
            ay += (v0.y + v1.y) + (v2.y + v3.y);
        }
    }
    ax += __shfl(ax, lane ^ 32);
    ay += __shfl(ay, lane ^ 32);
    if (lane < 32 && act) {
        float2 b2v = *(const float2*)&b2[2 * f];
        float2 sv = __half22float2(gp[w * 20 + f]);
        float2 o;
        o.x = fmaf(dc, ax + sv.x, b2v.x);
        o.y = fmaf(dc, ay + sv.y, b2v.y);
        *(float2*)&out[(size_t)w * C2 + 2 * f] = o;
    }
}

extern "C" void kernel_launch(void* const* d_in, const int* in_sizes, int n_in,
                              void* d_out, int out_size, void* d_ws, size_t ws_size,
                              hipStream_t stream) {
    const float* x   = (const float*)d_in[0];
    const int*   ei  = (const int*)d_in[1];
    const float* W1  = (const float*)d_in[2];
    const float* b1  = (const float*)d_in[3];
    const float* W2  = (const float*)d_in[4];
    const float* b2  = (const float*)d_in[5];
    float* out = (float*)d_out;

    const int N = in_sizes[0] / FIN;       // 100000
    const int E = in_sizes[1] / 2;         // 1600000
    const int* row = ei;
    const int* col = ei + E;

    const int NB = (N + 255) >> 8;         // 391 buckets
    const int T  = (E + TILE - 1) / TILE;  // 196 tiles
    const int EP = E + NB * 2048 + 8192;   // padded esrc + prefetch tail guard

    // workspace layout — ALL large buffers 256-B aligned (R23 lesson)
    char* ws = (char*)d_ws;
    size_t off = 0;
    auto align256 = [&off]() { off = (off + 255) & ~(size_t)255; };
    int*    bucketCnt = (int*)(ws + off);    off += (size_t)NB * 4;
    int*    goff      = (int*)(ws + off);    off += (size_t)NB * 4;
    align256();
    int*    deg       = (int*)(ws + off);    off += (size_t)N * 4;
    align256();
    int*    rowptr    = (int*)(ws + off);    off += (size_t)N * 4;
    align256();
    int*    pairs     = (int*)(ws + off);    off += (size_t)E * 4;
    align256();
    int*    esrc      = (int*)(ws + off);    off += (size_t)EP * 4;
    align256();
    _Float16* W1th    = (_Float16*)(ws + off); off += (size_t)H1 * WTS * 2;
    align256();
    _Float16* W1tl    = (_Float16*)(ws + off); off += (size_t)H1 * WTS * 2;
    align256();
    _Float16* W2th    = (_Float16*)(ws + off); off += (size_t)48 * W2TS * 2;
    align256();
    _Float16* W2tl    = (_Float16*)(ws + off); off += (size_t)48 * W2TS * 2;
    align256();
    __half* h1        = (__half*)(ws + off); off += (size_t)(N + 1) * H1 * 2;   // 128-B rows
    align256();
    __half* g         = (__half*)(ws + off); off += (size_t)(N + 1) * GP * 2;

    int gblocks = (N + 63) / 64;           // 1563

    // weight prep + zeroing + sentinels (parallel, coalesced) — before csr
    k_wprep<<<(FIN * H1 + 48 * 64 + 52 + 255) / 256, 256, 0, stream>>>(
        W1, W1th, W1tl, W2, W2th, W2tl, bucketCnt, goff, h1, g, NB, N);

    // fused histogram + scatter (cooperative: grid.sync between phases)
    {
        void* args[] = {(void*)&row, (void*)&col, (void*)&bucketCnt,
                        (void*)&goff, (void*)&pairs, (void*)&E, (void*)&NB};
        hipLaunchCooperativeKernel((void*)k_csr, dim3(T), dim3(512), args, 0, stream);
    }

    // bucket sort (local scans, LDS pairs staging, emits deg)
    k_bucket<<<NB, 512, 0, stream>>>(pairs, bucketCnt, rowptr, deg, esrc, N, NB);

    // GEMM1 via MFMA, writes h1' = (x@W1)*dinv (needs deg => after k_bucket)
    k_gemm1m<<<gblocks, 256, 0, stream>>>(x, W1th, W1tl, deg, h1, N);

    // layer 1 aggregation + bias + ReLU + GEMM2 via MFMA (fused), writes g' = h2*dinv
    k_agg1mm<<<gblocks, 512, 0, stream>>>(rowptr, deg, esrc, h1, b1, W2th, W2tl, g, N);

    // layer 2 aggregation + bias
    k_agg2<<<((size_t)N * 64 + 255) / 256, 256, 0, stream>>>(rowptr, deg, esrc, g, b2, out, N);
}

// Round 16
// 223.376 us; speedup vs baseline: 1.1739x; 1.1739x over previous
//
#include <hip/hip_runtime.h>
#include <hip/hip_fp16.h>

// GCN 2-layer forward on MI355X — R26: R24 restored (R25's cooperative
// hist+scatter fusion cost +33us in launch overhead — coop dispatch under
// graph capture is expensive; reverted) + int4-vectorized histogram loops
// in k_hist and k_scatter phase 1 (4 edges per VMEM instr, scalar tail).
// Kept from R24: 256-B aligned workspace (h1 row-gather alignment),
// MFMA GEMM1+GEMM2 (hi/lo fp16, fp32-grade), W2TS=68 bank floor, GP=40
// packed g, LDS pairs staging in k_bucket, rowptr/deg preload, act-guarded
// agg2, index prefetch, x8-padded esrc + tail guard, unroll-1 pins.
// Note: ~43us of measured time is the harness's 256MiB workspace re-poison
// fill (outside kernel control).
// Pipeline: wprep(+zero+sentinels) -> hist -> scatter -> bucket(deg) ->
//           gemm1m -> agg1mm -> agg2
// d_in: [0]=x (N*128 f32), [1]=edge_index (2*E i32), [2]=W1 (128*64),
//       [3]=b1 (64), [4]=W2 (64*40), [5]=b2 (40)
// d_out: N*40 f32

#define FIN 128
#define H1  64
#define C2  40
#define GP  40            // packed row stride (halves) for g => 80 B rows
#define TILE 8192         // edges per hist/scatter tile
#define BCAP 7168         // padded bucket capacity (mean 4096 + <=1792 pad)
#define STAGE_CAP 4608    // LDS pairs-staging capacity (mean 4092 + 8 sigma)
#define WTS 132           // padded W1t row stride (halves): bank-conflict-free
#define W2TS 68           // padded W2t/hs row stride (halves): 34-dword => bank floor

typedef _Float16 half4_t __attribute__((ext_vector_type(4)));
typedef float float4_t __attribute__((ext_vector_type(4)));

// ---------- W1/W2 planes; zero bucketCnt+goff; sentinel rows ----------
__global__ __launch_bounds__(256) void k_wprep(const float* __restrict__ W1,
                                               _Float16* __restrict__ W1th,
                                               _Float16* __restrict__ W1tl,
                                               const float* __restrict__ W2,
                                               _Float16* __restrict__ W2th,
                                               _Float16* __restrict__ W2tl,
                                               int* __restrict__ bucketCnt,
                                               int* __restrict__ goff,
                                               __half* __restrict__ h1,
                                               __half* __restrict__ g,
                                               int NB, int N) {
    int idx = blockIdx.x * 256 + threadIdx.x;
    if (idx < NB) { bucketCnt[idx] = 0; goff[idx] = 0; }
    if (idx < FIN * H1) {
        // W1 [k][o] -> planes [o][WTS]; consecutive idx = consecutive o (coalesced read)
        int k = idx >> 6, o = idx & 63;
        float wv = W1[k * H1 + o];
        _Float16 hi = (_Float16)wv;
        W1th[o * WTS + k] = hi;
        W1tl[o * WTS + k] = (_Float16)(wv - (float)hi);
    } else if (idx < FIN * H1 + 48 * 64) {
        // W2 [k][c] -> planes [n][W2TS], n<48 (cols 40-47 zero); coalesced over n
        int i = idx - FIN * H1;
        int kk = i / 48, n = i % 48;
        float wv = (n < C2) ? W2[kk * C2 + n] : 0.f;
        _Float16 hi = (_Float16)wv;
        W2th[n * W2TS + kk] = hi;
        W2tl[n * W2TS + kk] = (_Float16)(wv - (float)hi);
    } else if (idx < FIN * H1 + 48 * 64 + 32) {
        // sentinel row h1[N] (64 halves = 32 uints): pad entries src==N -> 0
        ((unsigned*)(h1 + (size_t)N * H1))[idx - (FIN * H1 + 48 * 64)] = 0u;
    } else if (idx < FIN * H1 + 48 * 64 + 52) {
        // sentinel row g[N] (40 halves = 20 uints)
        ((unsigned*)(g + (size_t)N * GP))[idx - (FIN * H1 + 48 * 64 + 32)] = 0u;
    }
}

// ---------- histogram: per-bucket counts only (LDS atomics, int4 loads) ----------
__global__ __launch_bounds__(256) void k_hist(const int* __restrict__ col, int E,
                                              int* __restrict__ bucketCnt, int NB) {
    __shared__ int lh[512];
    int t = threadIdx.x;
    for (int i = t; i < NB; i += 256) lh[i] = 0;
    __syncthreads();
    int base = blockIdx.x * TILE;
    int cnt = min(TILE, E - base);
    int cnt4 = cnt & ~3;
    for (int i = t * 4; i < cnt4; i += 1024) {
        int4 c4 = *(const int4*)&col[base + i];
        atomicAdd(&lh[c4.x >> 8], 1);
        atomicAdd(&lh[c4.y >> 8], 1);
        atomicAdd(&lh[c4.z >> 8], 1);
        atomicAdd(&lh[c4.w >> 8], 1);
    }
    for (int i = cnt4 + t; i < cnt; i += 256) atomicAdd(&lh[col[base + i] >> 8], 1);
    __syncthreads();
    for (int b = t; b < NB; b += 256) if (lh[b]) atomicAdd(&bucketCnt[b], lh[b]);
}

// ---------- scatter into bucket-contiguous chunks (packed pairs) ----------
// packed: bits 0..23 = src row, bits 24..31 = dest low 8.
// Bucket bases computed locally from final bucketCnt; chunk claim via goff.
__global__ __launch_bounds__(512) void k_scatter(const int* __restrict__ row,
                                                 const int* __restrict__ col,
                                                 const int* __restrict__ bucketCnt,
                                                 int* __restrict__ goff,
                                                 int* __restrict__ pairs,
                                                 int E, int NB) {
    __shared__ int2 stage[TILE];         // 64 KB
    __shared__ int lcnt[512];
    __shared__ int lex[512];
    __shared__ int gbase[512];
    __shared__ int scs[512];
    int t = threadIdx.x, tile = blockIdx.x;
    int base = tile * TILE;
    int cnt = min(TILE, E - base);

    // local exclusive scan of bucketCnt -> rex (thread t owns bucket t)
    int bc = (t < NB) ? bucketCnt[t] : 0;
    scs[t] = bc;
    __syncthreads();
    for (int off = 1; off < 512; off <<= 1) {
        int u = (t >= off) ? scs[t - off] : 0;
        __syncthreads();
        scs[t] += u;
        __syncthreads();
    }
    int rex = scs[t] - bc;

    lcnt[t] = 0;
    __syncthreads();
    {   // phase-1 histogram: int4 loads (4 edges/VMEM), scalar tail
        int cnt4 = cnt & ~3;
        for (int i = t * 4; i < cnt4; i += 2048) {
            int4 c4 = *(const int4*)&col[base + i];
            atomicAdd(&lcnt[c4.x >> 8], 1);
            atomicAdd(&lcnt[c4.y >> 8], 1);
            atomicAdd(&lcnt[c4.z >> 8], 1);
            atomicAdd(&lcnt[c4.w >> 8], 1);
        }
        for (int i = cnt4 + t; i < cnt; i += 512) atomicAdd(&lcnt[col[base + i] >> 8], 1);
    }
    __syncthreads();

    int myc = lcnt[t];
    lex[t] = myc;
    __syncthreads();
    for (int off = 1; off < 512; off <<= 1) {
        int u = (t >= off) ? lex[t - off] : 0;
        __syncthreads();
        lex[t] += u;
        __syncthreads();
    }
    int ex = lex[t] - myc;
    __syncthreads();
    lex[t] = ex;
    lcnt[t] = ex;                         // local cursor
    if (t < NB && myc > 0) gbase[t] = rex + atomicAdd(&goff[t], myc);
    __syncthreads();

    for (int i = t; i < cnt; i += 512) {
        int r = row[base + i], c = col[base + i];
        int lpos = atomicAdd(&lcnt[c >> 8], 1);
        stage[lpos] = make_int2(r, c);
    }
    __syncthreads();

    for (int i = t; i < cnt; i += 512) {
        int2 p = stage[i];
        int b = p.y >> 8;
        pairs[gbase[b] + (i - lex[b])] = p.x | ((p.y & 255) << 24);
    }
}

// ---------- per-bucket sort by dest; LDS pairs staging; local base scans ----------
__global__ __launch_bounds__(512) void k_bucket(const int* __restrict__ pairs,
                                                const int* __restrict__ bucketCnt,
                                                int* __restrict__ rowptr,
                                                int* __restrict__ deg,
                                                int* __restrict__ esrc,
                                                int N, int NB) {
    __shared__ int dcnt[256];
    __shared__ int sr[256], sp[256];
    __shared__ int cur[256];
    __shared__ int bsc[512], bsp[512];   // bucket-level scans (raw, padded)
    __shared__ int sb[4];
    __shared__ int outbuf[BCAP];         // 28 KB
    __shared__ int pstage[STAGE_CAP];    // 18 KB: this bucket's pairs
    int t = threadIdx.x, b = blockIdx.x;
    int d0 = b << 8;
    int nd = min(256, N - d0);

    // local scans over bucketCnt: bstart = rawEx[b], pstart = padEx[b]
    int c0 = (t < NB) ? bucketCnt[t] : 0;
    int p0 = (t < NB) ? (((c0 + 7) & ~7) + 2048) : 0;
    bsc[t] = c0; bsp[t] = p0;
    __syncthreads();
    for (int off = 1; off < 512; off <<= 1) {
        int a = (t >= off) ? bsc[t - off] : 0;
        int bb = (t >= off) ? bsp[t - off] : 0;
        __syncthreads();
        bsc[t] += a; bsp[t] += bb;
        __syncthreads();
    }
    if (t == b) { sb[0] = bsc[b] - c0; sb[1] = c0; sb[2] = bsp[b] - p0; }
    __syncthreads();
    int bstart = sb[0];
    int cnt = sb[1];
    int pstart = sb[2];

    // stage this bucket's pairs in LDS (one coalesced global read)
    bool staged = (cnt <= STAGE_CAP);
    if (staged) {
        for (int i = t; i < cnt; i += 512) pstage[i] = pairs[bstart + i];
    }
    if (t < 256) dcnt[t] = 0;
    __syncthreads();
    for (int i = t; i < cnt; i += 512) {
        unsigned p = (unsigned)(staged ? pstage[i] : pairs[bstart + i]);
        atomicAdd(&dcnt[p >> 24], 1);
    }
    __syncthreads();

    int myc = 0, myp = 0;
    if (t < 256) {
        myc = dcnt[t];
        myp = (myc + 7) & ~7;
        sr[t] = myc; sp[t] = myp;
    }
    __syncthreads();
    for (int off = 1; off < 256; off <<= 1) {
        int a = 0, c2 = 0;
        if (t < 256 && t >= off) { a = sr[t - off]; c2 = sp[t - off]; }
        __syncthreads();
        if (t < 256) { sr[t] += a; sp[t] += c2; }
        __syncthreads();
    }
    if (t < 256) {
        int pex = sp[t] - myp;
        cur[t] = pex;
        if (t < nd) {
            rowptr[d0 + t] = pstart + pex;
            deg[d0 + t] = myc;            // degree for free
        }
    }
    __syncthreads();
    int pcnt = sp[255];

    if (pcnt <= BCAP) {
        for (int i = t; i < cnt; i += 512) {
            unsigned p = (unsigned)(staged ? pstage[i] : pairs[bstart + i]);
            int lpos = atomicAdd(&cur[p >> 24], 1);
            outbuf[lpos] = (int)(p & 0xFFFFFF);
        }
        __syncthreads();
        if (t < 256) {
            int pex = sp[t] - myp;
            for (int j = myc; j < myp; ++j) outbuf[pex + j] = N;   // sentinel pad
        }
        __syncthreads();
        for (int i = t; i < pcnt; i += 512) esrc[pstart + i] = outbuf[i];
    } else {
        for (int i = t; i < cnt; i += 512) {
            unsigned p = (unsigned)(staged ? pstage[i] : pairs[bstart + i]);
            int lpos = atomicAdd(&cur[p >> 24], 1);
            esrc[pstart + lpos] = (int)(p & 0xFFFFFF);
        }
        __syncthreads();
        if (t < 256) {
            int pex = sp[t] - myp;
            for (int j = myc; j < myp; ++j) esrc[pstart + pex + j] = N;
        }
    }
}

// ---------- GEMM1 via MFMA: h1' = (x@W1)*dinv, hi/lo fp16 split ----------
__global__ __launch_bounds__(256) void k_gemm1m(const float* __restrict__ x,
                                                const _Float16* __restrict__ W1th,
                                                const _Float16* __restrict__ W1tl,
                                                const int* __restrict__ deg,
                                                __half* __restrict__ h1, int N) {
    __shared__ alignas(16) _Float16 Wh[H1 * WTS];   // 16.5 KB
    __shared__ alignas(16) _Float16 Wl[H1 * WTS];   // 16.5 KB
    int t = threadIdx.x;

    {   // stage both planes: 8448 halves = 1056 uint4 each
        const uint4* sh = (const uint4*)W1th;
        const uint4* sl = (const uint4*)W1tl;
        uint4* dh = (uint4*)Wh;
        uint4* dl = (uint4*)Wl;
        for (int i = t; i < (H1 * WTS) / 8; i += 256) { dh[i] = sh[i]; dl[i] = sl[i]; }
    }

    int wv = t >> 6, l = t & 63;
    int col = l & 15;             // node within 16-tile (A-row lane index)
    int krow = l >> 4;            // 0..3
    int node = blockIdx.x * 64 + wv * 16 + col;
    int nodec = min(node, N - 1);

    // B fragments from x: lane holds x[node][kt*16 + krow*4 + 0..3]
    half4_t bh[8], bl[8];
    const float4* xr = (const float4*)(x + (size_t)nodec * FIN);
#pragma unroll
    for (int kt = 0; kt < 8; ++kt) {
        float4 v = xr[kt * 4 + krow];
        half4_t hi, lo;
        hi[0] = (_Float16)v.x; lo[0] = (_Float16)(v.x - (float)hi[0]);
        hi[1] = (_Float16)v.y; lo[1] = (_Float16)(v.y - (float)hi[1]);
        hi[2] = (_Float16)v.z; lo[2] = (_Float16)(v.z - (float)hi[2]);
        hi[3] = (_Float16)v.w; lo[3] = (_Float16)(v.w - (float)hi[3]);
        bh[kt] = hi; bl[kt] = lo;
    }
    float dcv = rsqrtf((float)deg[nodec] + 1.0f);
    __syncthreads();

    float4_t acc[4];
#pragma unroll
    for (int ot = 0; ot < 4; ++ot) acc[ot] = (float4_t){0.f, 0.f, 0.f, 0.f};

#pragma unroll
    for (int kt = 0; kt < 8; ++kt) {
#pragma unroll
        for (int ot = 0; ot < 4; ++ot) {
            int aoff = ((ot * 16 + col) * WTS + kt * 16 + krow * 4) >> 2;  // half4 units
            half4_t ah = ((const half4_t*)Wh)[aoff];
            half4_t al = ((const half4_t*)Wl)[aoff];
            acc[ot] = __builtin_amdgcn_mfma_f32_16x16x16f16(ah, bh[kt], acc[ot], 0, 0, 0);
            acc[ot] = __builtin_amdgcn_mfma_f32_16x16x16f16(ah, bl[kt], acc[ot], 0, 0, 0);
            acc[ot] = __builtin_amdgcn_mfma_f32_16x16x16f16(al, bh[kt], acc[ot], 0, 0, 0);
        }
    }

    if (node < N) {
#pragma unroll
        for (int ot = 0; ot < 4; ++ot) {
            union { __half h[4]; uint2 u; } pk;
#pragma unroll
            for (int r = 0; r < 4; ++r) pk.h[r] = __float2half_rn(acc[ot][r] * dcv);
            *(uint2*)&h1[(size_t)node * H1 + ot * 16 + krow * 4] = pk.u;
        }
    }
}

// ---------- fused agg1 + bias + ReLU + GEMM2(MFMA) per 64-node block ----------
// 512 threads = 8 waves. Aggregation: R17 shape + index prefetch; rowptr/deg
// preloaded into LDS. Epilogue: hs hi/lo planes (W2TS=68 bank floor).
// GEMM2: 12 16x16 MFMA tiles / 8 waves, 3 mfma/k-step.
__global__ __launch_bounds__(512) void k_agg1mm(const int* __restrict__ rowptr,
                                                const int* __restrict__ deg,
                                                const int* __restrict__ esrc,
                                                const __half* __restrict__ h1,
                                                const float* __restrict__ b1,
                                                const _Float16* __restrict__ W2th,
                                                const _Float16* __restrict__ W2tl,
                                                __half* __restrict__ g, int N) {
    __shared__ alignas(16) _Float16 hsh[64][W2TS];   // 8.7 KB
    __shared__ alignas(16) _Float16 hsl[64][W2TS];   // 8.7 KB
    __shared__ alignas(16) _Float16 Wth[48][W2TS];   // 6.5 KB
    __shared__ alignas(16) _Float16 Wtl[48][W2TS];   // 6.5 KB
    __shared__ float sdc[64];
    __shared__ int srp[64], sdg[64];
    int t = threadIdx.x;
    int node0 = blockIdx.x * 64;

    {   // stage W2t planes: 408 uint4 each
        const uint4* sh = (const uint4*)W2th;
        const uint4* sl = (const uint4*)W2tl;
        uint4* dh = (uint4*)Wth;
        uint4* dl = (uint4*)Wtl;
        for (int i = t; i < (48 * W2TS) / 8; i += 512) { dh[i] = sh[i]; dl[i] = sl[i]; }
    }
    if (t < 64) {   // coalesced rowptr/deg preload for the block's nodes
        int node = node0 + t;
        srp[t] = (node < N) ? rowptr[node] : 0;
        sdg[t] = (node < N) ? deg[node] : 0;
    }
    __syncthreads();

    int wv = t >> 6, lane = t & 63;
    int half = lane >> 5;                // edge-octet selector
    int f = lane & 31;                   // feature-pair index
    float2 b1v = *(const float2*)&b1[2 * f];
    const __half2* hp = (const __half2*)h1;

    // aggregation: 8 nodes per wave, sequential (R17 loop + index prefetch)
#pragma unroll 1
    for (int j = 0; j < 8; ++j) {
        int r = wv * 8 + j;
        int node = node0 + r;
        if (node >= N) {
            if (lane < 32) { *(unsigned*)&hsh[r][2 * f] = 0u; *(unsigned*)&hsl[r][2 * f] = 0u; }
            if (lane == 0) sdc[r] = 0.f;
            continue;
        }
        int start = srp[r], d = sdg[r];
        int d8 = (d + 7) & ~7;
        float dc = rsqrtf((float)d + 1.0f);
        float ax = 0.f, ay = 0.f;
        int i = 0;
        // prime: first iteration's indices (over-read past segment is safe)
        int4 sA = *(const int4*)&esrc[start + half * 8];
        int4 sB = *(const int4*)&esrc[start + half * 8 + 4];
#pragma unroll 1
        for (; i + 16 <= d8; i += 16) {
            int4 cA = sA, cB = sB;
            int nb = start + i + 16 + half * 8;
            sA = *(const int4*)&esrc[nb];        // next-iter indices in flight
            sB = *(const int4*)&esrc[nb + 4];    // under current gathers
            float2 v0 = __half22float2(hp[cA.x * 32 + f]);
            float2 v1 = __half22float2(hp[cA.y * 32 + f]);
            float2 v2 = __half22float2(hp[cA.z * 32 + f]);
            float2 v3 = __half22float2(hp[cA.w * 32 + f]);
            float2 v4 = __half22float2(hp[cB.x * 32 + f]);
            float2 v5 = __half22float2(hp[cB.y * 32 + f]);
            float2 v6 = __half22float2(hp[cB.z * 32 + f]);
            float2 v7 = __half22float2(hp[cB.w * 32 + f]);
            ax += ((v0.x + v1.x) + (v2.x + v3.x)) + ((v4.x + v5.x) + (v6.x + v7.x));
            ay += ((v0.y + v1.y) + (v2.y + v3.y)) + ((v4.y + v5.y) + (v6.y + v7.y));
        }
        if (i < d8) {                    // one 8-edge chunk: 4 per half
            int4 s = *(const int4*)&esrc[start + i + half * 4];
            float2 v0 = __half22float2(hp[s.x * 32 + f]);
            float2 v1 = __half22float2(hp[s.y * 32 + f]);
            float2 v2 = __half22float2(hp[s.z * 32 + f]);
            float2 v3 = __half22float2(hp[s.w * 32 + f]);
            ax += (v0.x + v1.x) + (v2.x + v3.x);
            ay += (v0.y + v1.y) + (v2.y + v3.y);
        }
        // cross-half reduce (both halves end with full sum)
        ax += __shfl(ax, lane ^ 32);
        ay += __shfl(ay, lane ^ 32);
        // self-loop (h1' already has one dinv factor) + bias + ReLU
        float2 sv = __half22float2(hp[node * 32 + f]);
        ax = fmaxf(fmaf(dc, ax + sv.x, b1v.x), 0.f);
        ay = fmaxf(fmaf(dc, ay + sv.y, b1v.y), 0.f);
        if (lane < 32) {
            // hi/lo fp16 split (exact): hs = hi + lo to ~2^-22
            _Float16 axh = (_Float16)ax;
            _Float16 ayh = (_Float16)ay;
            _Float16 axl = (_Float16)(ax - (float)axh);
            _Float16 ayl = (_Float16)(ay - (float)ayh);
            union { _Float16 h[2]; unsigned u; } ph, pl;
            ph.h[0] = axh; ph.h[1] = ayh;
            pl.h[0] = axl; pl.h[1] = ayl;
            *(unsigned*)&hsh[r][2 * f] = ph.u;
            *(unsigned*)&hsl[r][2 * f] = pl.u;
        }
        if (lane == 0) sdc[r] = dc;
    }
    __syncthreads();

    // GEMM2 via MFMA: D[64 nodes][48 cols] = hs(h/l) x W2t(h/l); 12 tiles / 8 waves.
    int l15 = lane & 15, kg = (lane >> 4) * 4;
#pragma unroll 1
    for (int tile = wv; tile < 12; tile += 8) {
        int mt = tile & 3, nt = tile >> 2;
        int arow = mt * 16 + l15;
        int bcol = nt * 16 + l15;
        float4_t acc = (float4_t){0.f, 0.f, 0.f, 0.f};
#pragma unroll
        for (int kt = 0; kt < 4; ++kt) {
            int ko = kt * 16 + kg;
            half4_t ah = *(const half4_t*)&hsh[arow][ko];
            half4_t al = *(const half4_t*)&hsl[arow][ko];
            half4_t bh = *(const half4_t*)&Wth[bcol][ko];
            half4_t bl = *(const half4_t*)&Wtl[bcol][ko];
            acc = __builtin_amdgcn_mfma_f32_16x16x16f16(ah, bh, acc, 0, 0, 0);
            acc = __builtin_amdgcn_mfma_f32_16x16x16f16(ah, bl, acc, 0, 0, 0);
            acc = __builtin_amdgcn_mfma_f32_16x16x16f16(al, bh, acc, 0, 0, 0);
        }
        int colo = nt * 16 + l15;
        if (colo < C2) {                 // cols 40-47 are zero; only <40 stored
#pragma unroll
            for (int r2 = 0; r2 < 4; ++r2) {
                int nd = mt * 16 + (lane >> 4) * 4 + r2;
                int node = node0 + nd;
                if (node < N) {
                    g[(size_t)node * GP + colo] = __float2half_rn(acc[r2] * sdc[nd]);
                }
            }
        }
    }
}

// ---------- agg2: wave per node, packed g rows, act-guarded + prefetch ----------
__global__ __launch_bounds__(256) void k_agg2(const int* __restrict__ rowptr,
                                              const int* __restrict__ deg,
                                              const int* __restrict__ esrc,
                                              const __half* __restrict__ g,
                                              const float* __restrict__ b2,
                                              float* __restrict__ out, int N) {
    int w = (int)((blockIdx.x * blockDim.x + threadIdx.x) >> 6);
    int lane = threadIdx.x & 63;
    if (w >= N) return;
    int half = lane >> 5;
    int f = lane & 31;                   // feature-pair; active f<20
    bool act = f < 20;
    const __half2* gp = (const __half2*)g;  // row stride 20 half2 (80 B)

    int start = rowptr[w], d = deg[w];
    int d8 = (d + 7) & ~7;
    float dc = rsqrtf((float)d + 1.0f);
    float ax = 0.f, ay = 0.f;
    if (act) {                           // f>=20 lanes: no gathers (saved 37.5%)
        int i = 0;
        int4 sA = *(const int4*)&esrc[start + half * 8];
        int4 sB = *(const int4*)&esrc[start + half * 8 + 4];
#pragma unroll 1
        for (; i + 16 <= d8; i += 16) {
            int4 cA = sA, cB = sB;
            int nb = start + i + 16 + half * 8;
            sA = *(const int4*)&esrc[nb];
            sB = *(const int4*)&esrc[nb + 4];
            float2 v0 = __half22float2(gp[cA.x * 20 + f]);
            float2 v1 = __half22float2(gp[cA.y * 20 + f]);
            float2 v2 = __half22float2(gp[cA.z * 20 + f]);
            float2 v3 = __half22float2(gp[cA.w * 20 + f]);
            float2 v4 = __half22float2(gp[cB.x * 20 + f]);
            float2 v5 = __half22float2(gp[cB.y * 20 + f]);
            float2 v6 = __half22float2(gp[cB.z * 20 + f]);
            float2 v7 = __half22float2(gp[cB.w * 20 + f]);
            ax += ((v0.x + v1.x) + (v2.x + v3.x)) + ((v4.x + v5.x) + (v6.x + v7.x));
            ay += ((v0.y + v1.y) + (v2.y + v3.y)) + ((v4.y + v5.y) + (v6.y + v7.y));
        }
        if (i < d8) {
            int4 s = *(const int4*)&esrc[start + i + half * 4];
            float2 v0 = __half22float2(gp[s.x * 20 + f]);
            float2 v1 = __half22float2(gp[s.y * 20 + f]);
            float2 v2 = __half22float2(gp[s.z * 20 + f]);
            float2 v3 = __half22float2(gp[s.w * 20 + f]);
            ax += (v0.x + v1.x) + (v2.x + v3.x);
            ay += (v0.y + v1.y) + (v2.y + v3.y);
        }
    }
    ax += __shfl(ax, lane ^ 32);
    ay += __shfl(ay, lane ^ 32);
    if (lane < 32 && act) {
        float2 b2v = *(const float2*)&b2[2 * f];
        float2 sv = __half22float2(gp[w * 20 + f]);
        float2 o;
        o.x = fmaf(dc, ax + sv.x, b2v.x);
        o.y = fmaf(dc, ay + sv.y, b2v.y);
        *(float2*)&out[(size_t)w * C2 + 2 * f] = o;
    }
}

extern "C" void kernel_launch(void* const* d_in, const int* in_sizes, int n_in,
                              void* d_out, int out_size, void* d_ws, size_t ws_size,
                              hipStream_t stream) {
    const float* x   = (const float*)d_in[0];
    const int*   ei  = (const int*)d_in[1];
    const float* W1  = (const float*)d_in[2];
    const float* b1  = (const float*)d_in[3];
    const float* W2  = (const float*)d_in[4];
    const float* b2  = (const float*)d_in[5];
    float* out = (float*)d_out;

    const int N = in_sizes[0] / FIN;       // 100000
    const int E = in_sizes[1] / 2;         // 1600000
    const int* row = ei;
    const int* col = ei + E;

    const int NB = (N + 255) >> 8;         // 391 buckets
    const int T  = (E + TILE - 1) / TILE;  // 196 tiles
    const int EP = E + NB * 2048 + 8192;   // padded esrc + prefetch tail guard

    // workspace layout — ALL large buffers 256-B aligned (R23 lesson)
    char* ws = (char*)d_ws;
    size_t off = 0;
    auto align256 = [&off]() { off = (off + 255) & ~(size_t)255; };
    int*    bucketCnt = (int*)(ws + off);    off += (size_t)NB * 4;
    int*    goff      = (int*)(ws + off);    off += (size_t)NB * 4;
    align256();
    int*    deg       = (int*)(ws + off);    off += (size_t)N * 4;
    align256();
    int*    rowptr    = (int*)(ws + off);    off += (size_t)N * 4;
    align256();
    int*    pairs     = (int*)(ws + off);    off += (size_t)E * 4;
    align256();
    int*    esrc      = (int*)(ws + off);    off += (size_t)EP * 4;
    align256();
    _Float16* W1th    = (_Float16*)(ws + off); off += (size_t)H1 * WTS * 2;
    align256();
    _Float16* W1tl    = (_Float16*)(ws + off); off += (size_t)H1 * WTS * 2;
    align256();
    _Float16* W2th    = (_Float16*)(ws + off); off += (size_t)48 * W2TS * 2;
    align256();
    _Float16* W2tl    = (_Float16*)(ws + off); off += (size_t)48 * W2TS * 2;
    align256();
    __half* h1        = (__half*)(ws + off); off += (size_t)(N + 1) * H1 * 2;   // 128-B rows
    align256();
    __half* g         = (__half*)(ws + off); off += (size_t)(N + 1) * GP * 2;

    int gblocks = (N + 63) / 64;           // 1563

    // weight prep + zeroing + sentinels (parallel, coalesced) — before hist
    k_wprep<<<(FIN * H1 + 48 * 64 + 52 + 255) / 256, 256, 0, stream>>>(
        W1, W1th, W1tl, W2, W2th, W2tl, bucketCnt, goff, h1, g, NB, N);

    // CSR build: bucket histogram -> chunk-claim scatter (local scan) ->
    // bucket sort (local scans, LDS pairs staging, emits deg)
    k_hist<<<T, 256, 0, stream>>>(col, E, bucketCnt, NB);
    k_scatter<<<T, 512, 0, stream>>>(row, col, bucketCnt, goff, pairs, E, NB);
    k_bucket<<<NB, 512, 0, stream>>>(pairs, bucketCnt, rowptr, deg, esrc, N, NB);

    // GEMM1 via MFMA, writes h1' = (x@W1)*dinv (needs deg => after k_bucket)
    k_gemm1m<<<gblocks, 256, 0, stream>>>(x, W1th, W1tl, deg, h1, N);

    // layer 1 aggregation + bias + ReLU + GEMM2 via MFMA (fused), writes g' = h2*dinv
    k_agg1mm<<<gblocks, 512, 0, stream>>>(rowptr, deg, esrc, h1, b1, W2th, W2tl, g, N);

    // layer 2 aggregation + bias
    k_agg2<<<((size_t)N * 64 + 255) / 256, 256, 0, stream>>>(rowptr, deg, esrc, g, b2, out, N);
}

// Round 17
// 221.225 us; speedup vs baseline: 1.1853x; 1.0097x over previous
//
#include <hip/hip_runtime.h>
#include <hip/hip_fp16.h>

// GCN 2-layer forward on MI355X — R27: R26 + (1) k_agg1mm re-tiled to 256
// threads / 32 nodes per block (3125 blocks): finer launch tail, occupancy
// cap 8 blocks/CU (was 4), LDS 22 KB. Loop bodies unchanged. GEMM2 = 6
// 16x16 tiles over 4 waves. (2) k_scatter placement pass int4-vectorized
// (2 VMEM per 4 edges, matching the histogram pass).
// Kept: 256-B aligned workspace, MFMA GEMM1+GEMM2 (hi/lo fp16, fp32-grade),
// W2TS=68 bank floor, GP=40 packed g, LDS pairs staging, rowptr/deg preload,
// act-guarded agg2, index prefetch, x8-padded esrc + tail guard, unroll-1.
// Note: ~43us of measured time is the harness's 256MiB workspace re-poison
// fill (outside kernel control).
// Pipeline: wprep(+zero+sentinels) -> hist -> scatter -> bucket(deg) ->
//           gemm1m -> agg1mm -> agg2
// d_in: [0]=x (N*128 f32), [1]=edge_index (2*E i32), [2]=W1 (128*64),
//       [3]=b1 (64), [4]=W2 (64*40), [5]=b2 (40)
// d_out: N*40 f32

#define FIN 128
#define H1  64
#define C2  40
#define GP  40            // packed row stride (halves) for g => 80 B rows
#define TILE 8192         // edges per hist/scatter tile
#define BCAP 7168         // padded bucket capacity (mean 4096 + <=1792 pad)
#define STAGE_CAP 4608    // LDS pairs-staging capacity (mean 4092 + 8 sigma)
#define WTS 132           // padded W1t row stride (halves): bank-conflict-free
#define W2TS 68           // padded W2t/hs row stride (halves): 34-dword => bank floor

typedef _Float16 half4_t __attribute__((ext_vector_type(4)));
typedef float float4_t __attribute__((ext_vector_type(4)));

// ---------- W1/W2 planes; zero bucketCnt+goff; sentinel rows ----------
__global__ __launch_bounds__(256) void k_wprep(const float* __restrict__ W1,
                                               _Float16* __restrict__ W1th,
                                               _Float16* __restrict__ W1tl,
                                               const float* __restrict__ W2,
                                               _Float16* __restrict__ W2th,
                                               _Float16* __restrict__ W2tl,
                                               int* __restrict__ bucketCnt,
                                               int* __restrict__ goff,
                                               __half* __restrict__ h1,
                                               __half* __restrict__ g,
                                               int NB, int N) {
    int idx = blockIdx.x * 256 + threadIdx.x;
    if (idx < NB) { bucketCnt[idx] = 0; goff[idx] = 0; }
    if (idx < FIN * H1) {
        // W1 [k][o] -> planes [o][WTS]; consecutive idx = consecutive o (coalesced read)
        int k = idx >> 6, o = idx & 63;
        float wv = W1[k * H1 + o];
        _Float16 hi = (_Float16)wv;
        W1th[o * WTS + k] = hi;
        W1tl[o * WTS + k] = (_Float16)(wv - (float)hi);
    } else if (idx < FIN * H1 + 48 * 64) {
        // W2 [k][c] -> planes [n][W2TS], n<48 (cols 40-47 zero); coalesced over n
        int i = idx - FIN * H1;
        int kk = i / 48, n = i % 48;
        float wv = (n < C2) ? W2[kk * C2 + n] : 0.f;
        _Float16 hi = (_Float16)wv;
        W2th[n * W2TS + kk] = hi;
        W2tl[n * W2TS + kk] = (_Float16)(wv - (float)hi);
    } else if (idx < FIN * H1 + 48 * 64 + 32) {
        // sentinel row h1[N] (64 halves = 32 uints): pad entries src==N -> 0
        ((unsigned*)(h1 + (size_t)N * H1))[idx - (FIN * H1 + 48 * 64)] = 0u;
    } else if (idx < FIN * H1 + 48 * 64 + 52) {
        // sentinel row g[N] (40 halves = 20 uints)
        ((unsigned*)(g + (size_t)N * GP))[idx - (FIN * H1 + 48 * 64 + 32)] = 0u;
    }
}

// ---------- histogram: per-bucket counts only (LDS atomics, int4 loads) ----------
__global__ __launch_bounds__(256) void k_hist(const int* __restrict__ col, int E,
                                              int* __restrict__ bucketCnt, int NB) {
    __shared__ int lh[512];
    int t = threadIdx.x;
    for (int i = t; i < NB; i += 256) lh[i] = 0;
    __syncthreads();
    int base = blockIdx.x * TILE;
    int cnt = min(TILE, E - base);
    int cnt4 = cnt & ~3;
    for (int i = t * 4; i < cnt4; i += 1024) {
        int4 c4 = *(const int4*)&col[base + i];
        atomicAdd(&lh[c4.x >> 8], 1);
        atomicAdd(&lh[c4.y >> 8], 1);
        atomicAdd(&lh[c4.z >> 8], 1);
        atomicAdd(&lh[c4.w >> 8], 1);
    }
    for (int i = cnt4 + t; i < cnt; i += 256) atomicAdd(&lh[col[base + i] >> 8], 1);
    __syncthreads();
    for (int b = t; b < NB; b += 256) if (lh[b]) atomicAdd(&bucketCnt[b], lh[b]);
}

// ---------- scatter into bucket-contiguous chunks (packed pairs) ----------
// packed: bits 0..23 = src row, bits 24..31 = dest low 8.
// Bucket bases computed locally from final bucketCnt; chunk claim via goff.
__global__ __launch_bounds__(512) void k_scatter(const int* __restrict__ row,
                                                 const int* __restrict__ col,
                                                 const int* __restrict__ bucketCnt,
                                                 int* __restrict__ goff,
                                                 int* __restrict__ pairs,
                                                 int E, int NB) {
    __shared__ int2 stage[TILE];         // 64 KB
    __shared__ int lcnt[512];
    __shared__ int lex[512];
    __shared__ int gbase[512];
    __shared__ int scs[512];
    int t = threadIdx.x, tile = blockIdx.x;
    int base = tile * TILE;
    int cnt = min(TILE, E - base);

    // local exclusive scan of bucketCnt -> rex (thread t owns bucket t)
    int bc = (t < NB) ? bucketCnt[t] : 0;
    scs[t] = bc;
    __syncthreads();
    for (int off = 1; off < 512; off <<= 1) {
        int u = (t >= off) ? scs[t - off] : 0;
        __syncthreads();
        scs[t] += u;
        __syncthreads();
    }
    int rex = scs[t] - bc;

    lcnt[t] = 0;
    __syncthreads();
    {   // phase-1 histogram: int4 loads (4 edges/VMEM), scalar tail
        int cnt4 = cnt & ~3;
        for (int i = t * 4; i < cnt4; i += 2048) {
            int4 c4 = *(const int4*)&col[base + i];
            atomicAdd(&lcnt[c4.x >> 8], 1);
            atomicAdd(&lcnt[c4.y >> 8], 1);
            atomicAdd(&lcnt[c4.z >> 8], 1);
            atomicAdd(&lcnt[c4.w >> 8], 1);
        }
        for (int i = cnt4 + t; i < cnt; i += 512) atomicAdd(&lcnt[col[base + i] >> 8], 1);
    }
    __syncthreads();

    int myc = lcnt[t];
    lex[t] = myc;
    __syncthreads();
    for (int off = 1; off < 512; off <<= 1) {
        int u = (t >= off) ? lex[t - off] : 0;
        __syncthreads();
        lex[t] += u;
        __syncthreads();
    }
    int ex = lex[t] - myc;
    __syncthreads();
    lex[t] = ex;
    lcnt[t] = ex;                         // local cursor
    if (t < NB && myc > 0) gbase[t] = rex + atomicAdd(&goff[t], myc);
    __syncthreads();

    {   // placement pass: int4 loads of row+col (2 VMEM per 4 edges)
        int cnt4 = cnt & ~3;
        for (int i = t * 4; i < cnt4; i += 2048) {
            int4 r4 = *(const int4*)&row[base + i];
            int4 c4 = *(const int4*)&col[base + i];
            int lp;
            lp = atomicAdd(&lcnt[c4.x >> 8], 1); stage[lp] = make_int2(r4.x, c4.x);
            lp = atomicAdd(&lcnt[c4.y >> 8], 1); stage[lp] = make_int2(r4.y, c4.y);
            lp = atomicAdd(&lcnt[c4.z >> 8], 1); stage[lp] = make_int2(r4.z, c4.z);
            lp = atomicAdd(&lcnt[c4.w >> 8], 1); stage[lp] = make_int2(r4.w, c4.w);
        }
        for (int i = cnt4 + t; i < cnt; i += 512) {
            int r = row[base + i], c = col[base + i];
            int lpos = atomicAdd(&lcnt[c >> 8], 1);
            stage[lpos] = make_int2(r, c);
        }
    }
    __syncthreads();

    for (int i = t; i < cnt; i += 512) {
        int2 p = stage[i];
        int b = p.y >> 8;
        pairs[gbase[b] + (i - lex[b])] = p.x | ((p.y & 255) << 24);
    }
}

// ---------- per-bucket sort by dest; LDS pairs staging; local base scans ----------
__global__ __launch_bounds__(512) void k_bucket(const int* __restrict__ pairs,
                                                const int* __restrict__ bucketCnt,
                                                int* __restrict__ rowptr,
                                                int* __restrict__ deg,
                                                int* __restrict__ esrc,
                                                int N, int NB) {
    __shared__ int dcnt[256];
    __shared__ int sr[256], sp[256];
    __shared__ int cur[256];
    __shared__ int bsc[512], bsp[512];   // bucket-level scans (raw, padded)
    __shared__ int sb[4];
    __shared__ int outbuf[BCAP];         // 28 KB
    __shared__ int pstage[STAGE_CAP];    // 18 KB: this bucket's pairs
    int t = threadIdx.x, b = blockIdx.x;
    int d0 = b << 8;
    int nd = min(256, N - d0);

    // local scans over bucketCnt: bstart = rawEx[b], pstart = padEx[b]
    int c0 = (t < NB) ? bucketCnt[t] : 0;
    int p0 = (t < NB) ? (((c0 + 7) & ~7) + 2048) : 0;
    bsc[t] = c0; bsp[t] = p0;
    __syncthreads();
    for (int off = 1; off < 512; off <<= 1) {
        int a = (t >= off) ? bsc[t - off] : 0;
        int bb = (t >= off) ? bsp[t - off] : 0;
        __syncthreads();
        bsc[t] += a; bsp[t] += bb;
        __syncthreads();
    }
    if (t == b) { sb[0] = bsc[b] - c0; sb[1] = c0; sb[2] = bsp[b] - p0; }
    __syncthreads();
    int bstart = sb[0];
    int cnt = sb[1];
    int pstart = sb[2];

    // stage this bucket's pairs in LDS (one coalesced global read)
    bool staged = (cnt <= STAGE_CAP);
    if (staged) {
        for (int i = t; i < cnt; i += 512) pstage[i] = pairs[bstart + i];
    }
    if (t < 256) dcnt[t] = 0;
    __syncthreads();
    for (int i = t; i < cnt; i += 512) {
        unsigned p = (unsigned)(staged ? pstage[i] : pairs[bstart + i]);
        atomicAdd(&dcnt[p >> 24], 1);
    }
    __syncthreads();

    int myc = 0, myp = 0;
    if (t < 256) {
        myc = dcnt[t];
        myp = (myc + 7) & ~7;
        sr[t] = myc; sp[t] = myp;
    }
    __syncthreads();
    for (int off = 1; off < 256; off <<= 1) {
        int a = 0, c2 = 0;
        if (t < 256 && t >= off) { a = sr[t - off]; c2 = sp[t - off]; }
        __syncthreads();
        if (t < 256) { sr[t] += a; sp[t] += c2; }
        __syncthreads();
    }
    if (t < 256) {
        int pex = sp[t] - myp;
        cur[t] = pex;
        if (t < nd) {
            rowptr[d0 + t] = pstart + pex;
            deg[d0 + t] = myc;            // degree for free
        }
    }
    __syncthreads();
    int pcnt = sp[255];

    if (pcnt <= BCAP) {
        for (int i = t; i < cnt; i += 512) {
            unsigned p = (unsigned)(staged ? pstage[i] : pairs[bstart + i]);
            int lpos = atomicAdd(&cur[p >> 24], 1);
            outbuf[lpos] = (int)(p & 0xFFFFFF);
        }
        __syncthreads();
        if (t < 256) {
            int pex = sp[t] - myp;
            for (int j = myc; j < myp; ++j) outbuf[pex + j] = N;   // sentinel pad
        }
        __syncthreads();
        for (int i = t; i < pcnt; i += 512) esrc[pstart + i] = outbuf[i];
    } else {
        for (int i = t; i < cnt; i += 512) {
            unsigned p = (unsigned)(staged ? pstage[i] : pairs[bstart + i]);
            int lpos = atomicAdd(&cur[p >> 24], 1);
            esrc[pstart + lpos] = (int)(p & 0xFFFFFF);
        }
        __syncthreads();
        if (t < 256) {
            int pex = sp[t] - myp;
            for (int j = myc; j < myp; ++j) esrc[pstart + pex + j] = N;
        }
    }
}

// ---------- GEMM1 via MFMA: h1' = (x@W1)*dinv, hi/lo fp16 split ----------
__global__ __launch_bounds__(256) void k_gemm1m(const float* __restrict__ x,
                                                const _Float16* __restrict__ W1th,
                                                const _Float16* __restrict__ W1tl,
                                                const int* __restrict__ deg,
                                                __half* __restrict__ h1, int N) {
    __shared__ alignas(16) _Float16 Wh[H1 * WTS];   // 16.5 KB
    __shared__ alignas(16) _Float16 Wl[H1 * WTS];   // 16.5 KB
    int t = threadIdx.x;

    {   // stage both planes: 8448 halves = 1056 uint4 each
        const uint4* sh = (const uint4*)W1th;
        const uint4* sl = (const uint4*)W1tl;
        uint4* dh = (uint4*)Wh;
        uint4* dl = (uint4*)Wl;
        for (int i = t; i < (H1 * WTS) / 8; i += 256) { dh[i] = sh[i]; dl[i] = sl[i]; }
    }

    int wv = t >> 6, l = t & 63;
    int col = l & 15;             // node within 16-tile (A-row lane index)
    int krow = l >> 4;            // 0..3
    int node = blockIdx.x * 64 + wv * 16 + col;
    int nodec = min(node, N - 1);

    // B fragments from x: lane holds x[node][kt*16 + krow*4 + 0..3]
    half4_t bh[8], bl[8];
    const float4* xr = (const float4*)(x + (size_t)nodec * FIN);
#pragma unroll
    for (int kt = 0; kt < 8; ++kt) {
        float4 v = xr[kt * 4 + krow];
        half4_t hi, lo;
        hi[0] = (_Float16)v.x; lo[0] = (_Float16)(v.x - (float)hi[0]);
        hi[1] = (_Float16)v.y; lo[1] = (_Float16)(v.y - (float)hi[1]);
        hi[2] = (_Float16)v.z; lo[2] = (_Float16)(v.z - (float)hi[2]);
        hi[3] = (_Float16)v.w; lo[3] = (_Float16)(v.w - (float)hi[3]);
        bh[kt] = hi; bl[kt] = lo;
    }
    float dcv = rsqrtf((float)deg[nodec] + 1.0f);
    __syncthreads();

    float4_t acc[4];
#pragma unroll
    for (int ot = 0; ot < 4; ++ot) acc[ot] = (float4_t){0.f, 0.f, 0.f, 0.f};

#pragma unroll
    for (int kt = 0; kt < 8; ++kt) {
#pragma unroll
        for (int ot = 0; ot < 4; ++ot) {
            int aoff = ((ot * 16 + col) * WTS + kt * 16 + krow * 4) >> 2;  // half4 units
            half4_t ah = ((const half4_t*)Wh)[aoff];
            half4_t al = ((const half4_t*)Wl)[aoff];
            acc[ot] = __builtin_amdgcn_mfma_f32_16x16x16f16(ah, bh[kt], acc[ot], 0, 0, 0);
            acc[ot] = __builtin_amdgcn_mfma_f32_16x16x16f16(ah, bl[kt], acc[ot], 0, 0, 0);
            acc[ot] = __builtin_amdgcn_mfma_f32_16x16x16f16(al, bh[kt], acc[ot], 0, 0, 0);
        }
    }

    if (node < N) {
#pragma unroll
        for (int ot = 0; ot < 4; ++ot) {
            union { __half h[4]; uint2 u; } pk;
#pragma unroll
            for (int r = 0; r < 4; ++r) pk.h[r] = __float2half_rn(acc[ot][r] * dcv);
            *(uint2*)&h1[(size_t)node * H1 + ot * 16 + krow * 4] = pk.u;
        }
    }
}

// ---------- fused agg1 + bias + ReLU + GEMM2(MFMA) per 32-node block ----------
// 256 threads = 4 waves (R27: halved block for finer tail + 8 blocks/CU).
// Aggregation: R17 shape + index prefetch; rowptr/deg preloaded into LDS.
// Epilogue: hs hi/lo planes (W2TS=68 bank floor). GEMM2: 6 16x16 MFMA
// tiles (2 M x 3 N) over 4 waves, 3 mfma/k-step.
__global__ __launch_bounds__(256) void k_agg1mm(const int* __restrict__ rowptr,
                                                const int* __restrict__ deg,
                                                const int* __restrict__ esrc,
                                                const __half* __restrict__ h1,
                                                const float* __restrict__ b1,
                                                const _Float16* __restrict__ W2th,
                                                const _Float16* __restrict__ W2tl,
                                                __half* __restrict__ g, int N) {
    __shared__ alignas(16) _Float16 hsh[32][W2TS];   // 4.3 KB
    __shared__ alignas(16) _Float16 hsl[32][W2TS];   // 4.3 KB
    __shared__ alignas(16) _Float16 Wth[48][W2TS];   // 6.5 KB
    __shared__ alignas(16) _Float16 Wtl[48][W2TS];   // 6.5 KB
    __shared__ float sdc[32];
    __shared__ int srp[32], sdg[32];
    int t = threadIdx.x;
    int node0 = blockIdx.x * 32;

    {   // stage W2t planes: 408 uint4 each
        const uint4* sh = (const uint4*)W2th;
        const uint4* sl = (const uint4*)W2tl;
        uint4* dh = (uint4*)Wth;
        uint4* dl = (uint4*)Wtl;
        for (int i = t; i < (48 * W2TS) / 8; i += 256) { dh[i] = sh[i]; dl[i] = sl[i]; }
    }
    if (t < 32) {   // coalesced rowptr/deg preload for the block's nodes
        int node = node0 + t;
        srp[t] = (node < N) ? rowptr[node] : 0;
        sdg[t] = (node < N) ? deg[node] : 0;
    }
    __syncthreads();

    int wv = t >> 6, lane = t & 63;
    int half = lane >> 5;                // edge-octet selector
    int f = lane & 31;                   // feature-pair index
    float2 b1v = *(const float2*)&b1[2 * f];
    const __half2* hp = (const __half2*)h1;

    // aggregation: 8 nodes per wave, sequential (R17 loop + index prefetch)
#pragma unroll 1
    for (int j = 0; j < 8; ++j) {
        int r = wv * 8 + j;
        int node = node0 + r;
        if (node >= N) {
            if (lane < 32) { *(unsigned*)&hsh[r][2 * f] = 0u; *(unsigned*)&hsl[r][2 * f] = 0u; }
            if (lane == 0) sdc[r] = 0.f;
            continue;
        }
        int start = srp[r], d = sdg[r];
        int d8 = (d + 7) & ~7;
        float dc = rsqrtf((float)d + 1.0f);
        float ax = 0.f, ay = 0.f;
        int i = 0;
        // prime: first iteration's indices (over-read past segment is safe)
        int4 sA = *(const int4*)&esrc[start + half * 8];
        int4 sB = *(const int4*)&esrc[start + half * 8 + 4];
#pragma unroll 1
        for (; i + 16 <= d8; i += 16) {
            int4 cA = sA, cB = sB;
            int nb = start + i + 16 + half * 8;
            sA = *(const int4*)&esrc[nb];        // next-iter indices in flight
            sB = *(const int4*)&esrc[nb + 4];    // under current gathers
            float2 v0 = __half22float2(hp[cA.x * 32 + f]);
            float2 v1 = __half22float2(hp[cA.y * 32 + f]);
            float2 v2 = __half22float2(hp[cA.z * 32 + f]);
            float2 v3 = __half22float2(hp[cA.w * 32 + f]);
            float2 v4 = __half22float2(hp[cB.x * 32 + f]);
            float2 v5 = __half22float2(hp[cB.y * 32 + f]);
            float2 v6 = __half22float2(hp[cB.z * 32 + f]);
            float2 v7 = __half22float2(hp[cB.w * 32 + f]);
            ax += ((v0.x + v1.x) + (v2.x + v3.x)) + ((v4.x + v5.x) + (v6.x + v7.x));
            ay += ((v0.y + v1.y) + (v2.y + v3.y)) + ((v4.y + v5.y) + (v6.y + v7.y));
        }
        if (i < d8) {                    // one 8-edge chunk: 4 per half
            int4 s = *(const int4*)&esrc[start + i + half * 4];
            float2 v0 = __half22float2(hp[s.x * 32 + f]);
            float2 v1 = __half22float2(hp[s.y * 32 + f]);
            float2 v2 = __half22float2(hp[s.z * 32 + f]);
            float2 v3 = __half22float2(hp[s.w * 32 + f]);
            ax += (v0.x + v1.x) + (v2.x + v3.x);
            ay += (v0.y + v1.y) + (v2.y + v3.y);
        }
        // cross-half reduce (both halves end with full sum)
        ax += __shfl(ax, lane ^ 32);
        ay += __shfl(ay, lane ^ 32);
        // self-loop (h1' already has one dinv factor) + bias + ReLU
        float2 sv = __half22float2(hp[node * 32 + f]);
        ax = fmaxf(fmaf(dc, ax + sv.x, b1v.x), 0.f);
        ay = fmaxf(fmaf(dc, ay + sv.y, b1v.y), 0.f);
        if (lane < 32) {
            // hi/lo fp16 split (exact): hs = hi + lo to ~2^-22
            _Float16 axh = (_Float16)ax;
            _Float16 ayh = (_Float16)ay;
            _Float16 axl = (_Float16)(ax - (float)axh);
            _Float16 ayl = (_Float16)(ay - (float)ayh);
            union { _Float16 h[2]; unsigned u; } ph, pl;
            ph.h[0] = axh; ph.h[1] = ayh;
            pl.h[0] = axl; pl.h[1] = ayl;
            *(unsigned*)&hsh[r][2 * f] = ph.u;
            *(unsigned*)&hsl[r][2 * f] = pl.u;
        }
        if (lane == 0) sdc[r] = dc;
    }
    __syncthreads();

    // GEMM2 via MFMA: D[32 nodes][48 cols] = hs(h/l) x W2t(h/l); 6 tiles / 4 waves.
    int l15 = lane & 15, kg = (lane >> 4) * 4;
#pragma unroll 1
    for (int tile = wv; tile < 6; tile += 4) {
        int mt = tile & 1, nt = tile >> 1;
        int arow = mt * 16 + l15;
        int bcol = nt * 16 + l15;
        float4_t acc = (float4_t){0.f, 0.f, 0.f, 0.f};
#pragma unroll
        for (int kt = 0; kt < 4; ++kt) {
            int ko = kt * 16 + kg;
            half4_t ah = *(const half4_t*)&hsh[arow][ko];
            half4_t al = *(const half4_t*)&hsl[arow][ko];
            half4_t bh = *(const half4_t*)&Wth[bcol][ko];
            half4_t bl = *(const half4_t*)&Wtl[bcol][ko];
            acc = __builtin_amdgcn_mfma_f32_16x16x16f16(ah, bh, acc, 0, 0, 0);
            acc = __builtin_amdgcn_mfma_f32_16x16x16f16(ah, bl, acc, 0, 0, 0);
            acc = __builtin_amdgcn_mfma_f32_16x16x16f16(al, bh, acc, 0, 0, 0);
        }
        int colo = nt * 16 + l15;
        if (colo < C2) {                 // cols 40-47 are zero; only <40 stored
#pragma unroll
            for (int r2 = 0; r2 < 4; ++r2) {
                int nd = mt * 16 + (lane >> 4) * 4 + r2;
                int node = node0 + nd;
                if (node < N) {
                    g[(size_t)node * GP + colo] = __float2half_rn(acc[r2] * sdc[nd]);
                }
            }
        }
    }
}

// ---------- agg2: wave per node, packed g rows, act-guarded + prefetch ----------
__global__ __launch_bounds__(256) void k_agg2(const int* __restrict__ rowptr,
                                              const int* __restrict__ deg,
                                              const int* __restrict__ esrc,
                                              const __half* __restrict__ g,
                                              const float* __restrict__ b2,
                                              float* __restrict__ out, int N) {
    int w = (int)((blockIdx.x * blockDim.x + threadIdx.x) >> 6);
    int lane = threadIdx.x & 63;
    if (w >= N) return;
    int half = lane >> 5;
    int f = lane & 31;                   // feature-pair; active f<20
    bool act = f < 20;
    const __half2* gp = (const __half2*)g;  // row stride 20 half2 (80 B)

    int start = rowptr[w], d = deg[w];
    int d8 = (d + 7) & ~7;
    float dc = rsqrtf((float)d + 1.0f);
    float ax = 0.f, ay = 0.f;
    if (act) {                           // f>=20 lanes: no gathers (saved 37.5%)
        int i = 0;
        int4 sA = *(const int4*)&esrc[start + half * 8];
        int4 sB = *(const int4*)&esrc[start + half * 8 + 4];
#pragma unroll 1
        for (; i + 16 <= d8; i += 16) {
            int4 cA = sA, cB = sB;
            int nb = start + i + 16 + half * 8;
            sA = *(const int4*)&esrc[nb];
            sB = *(const int4*)&esrc[nb + 4];
            float2 v0 = __half22float2(gp[cA.x * 20 + f]);
            float2 v1 = __half22float2(gp[cA.y * 20 + f]);
            float2 v2 = __half22float2(gp[cA.z * 20 + f]);
            float2 v3 = __half22float2(gp[cA.w * 20 + f]);
            float2 v4 = __half22float2(gp[cB.x * 20 + f]);
            float2 v5 = __half22float2(gp[cB.y * 20 + f]);
            float2 v6 = __half22float2(gp[cB.z * 20 + f]);
            float2 v7 = __half22float2(gp[cB.w * 20 + f]);
            ax += ((v0.x + v1.x) + (v2.x + v3.x)) + ((v4.x + v5.x) + (v6.x + v7.x));
            ay += ((v0.y + v1.y) + (v2.y + v3.y)) + ((v4.y + v5.y) + (v6.y + v7.y));
        }
        if (i < d8) {
            int4 s = *(const int4*)&esrc[start + i + half * 4];
            float2 v0 = __half22float2(gp[s.x * 20 + f]);
            float2 v1 = __half22float2(gp[s.y * 20 + f]);
            float2 v2 = __half22float2(gp[s.z * 20 + f]);
            float2 v3 = __half22float2(gp[s.w * 20 + f]);
            ax += (v0.x + v1.x) + (v2.x + v3.x);
            ay += (v0.y + v1.y) + (v2.y + v3.y);
        }
    }
    ax += __shfl(ax, lane ^ 32);
    ay += __shfl(ay, lane ^ 32);
    if (lane < 32 && act) {
        float2 b2v = *(const float2*)&b2[2 * f];
        float2 sv = __half22float2(gp[w * 20 + f]);
        float2 o;
        o.x = fmaf(dc, ax + sv.x, b2v.x);
        o.y = fmaf(dc, ay + sv.y, b2v.y);
        *(float2*)&out[(size_t)w * C2 + 2 * f] = o;
    }
}

extern "C" void kernel_launch(void* const* d_in, const int* in_sizes, int n_in,
                              void* d_out, int out_size, void* d_ws, size_t ws_size,
                              hipStream_t stream) {
    const float* x   = (const float*)d_in[0];
    const int*   ei  = (const int*)d_in[1];
    const float* W1  = (const float*)d_in[2];
    const float* b1  = (const float*)d_in[3];
    const float* W2  = (const float*)d_in[4];
    const float* b2  = (const float*)d_in[5];
    float* out = (float*)d_out;

    const int N = in_sizes[0] / FIN;       // 100000
    const int E = in_sizes[1] / 2;         // 1600000
    const int* row = ei;
    const int* col = ei + E;

    const int NB = (N + 255) >> 8;         // 391 buckets
    const int T  = (E + TILE - 1) / TILE;  // 196 tiles
    const int EP = E + NB * 2048 + 8192;   // padded esrc + prefetch tail guard

    // workspace layout — ALL large buffers 256-B aligned (R23 lesson)
    char* ws = (char*)d_ws;
    size_t off = 0;
    auto align256 = [&off]() { off = (off + 255) & ~(size_t)255; };
    int*    bucketCnt = (int*)(ws + off);    off += (size_t)NB * 4;
    int*    goff      = (int*)(ws + off);    off += (size_t)NB * 4;
    align256();
    int*    deg       = (int*)(ws + off);    off += (size_t)N * 4;
    align256();
    int*    rowptr    = (int*)(ws + off);    off += (size_t)N * 4;
    align256();
    int*    pairs     = (int*)(ws + off);    off += (size_t)E * 4;
    align256();
    int*    esrc      = (int*)(ws + off);    off += (size_t)EP * 4;
    align256();
    _Float16* W1th    = (_Float16*)(ws + off); off += (size_t)H1 * WTS * 2;
    align256();
    _Float16* W1tl    = (_Float16*)(ws + off); off += (size_t)H1 * WTS * 2;
    align256();
    _Float16* W2th    = (_Float16*)(ws + off); off += (size_t)48 * W2TS * 2;
    align256();
    _Float16* W2tl    = (_Float16*)(ws + off); off += (size_t)48 * W2TS * 2;
    align256();
    __half* h1        = (__half*)(ws + off); off += (size_t)(N + 1) * H1 * 2;   // 128-B rows
    align256();
    __half* g         = (__half*)(ws + off); off += (size_t)(N + 1) * GP * 2;

    // weight prep + zeroing + sentinels (parallel, coalesced) — before hist
    k_wprep<<<(FIN * H1 + 48 * 64 + 52 + 255) / 256, 256, 0, stream>>>(
        W1, W1th, W1tl, W2, W2th, W2tl, bucketCnt, goff, h1, g, NB, N);

    // CSR build: bucket histogram -> chunk-claim scatter (local scan) ->
    // bucket sort (local scans, LDS pairs staging, emits deg)
    k_hist<<<T, 256, 0, stream>>>(col, E, bucketCnt, NB);
    k_scatter<<<T, 512, 0, stream>>>(row, col, bucketCnt, goff, pairs, E, NB);
    k_bucket<<<NB, 512, 0, stream>>>(pairs, bucketCnt, rowptr, deg, esrc, N, NB);

    // GEMM1 via MFMA, writes h1' = (x@W1)*dinv (needs deg => after k_bucket)
    k_gemm1m<<<(N + 63) / 64, 256, 0, stream>>>(x, W1th, W1tl, deg, h1, N);

    // layer 1 aggregation + bias + ReLU + GEMM2 via MFMA (fused, 32-node blocks)
    k_agg1mm<<<(N + 31) / 32, 256, 0, stream>>>(rowptr, deg, esrc, h1, b1, W2th, W2tl, g, N);

    // layer 2 aggregation + bias
    k_agg2<<<((size_t)N * 64 + 255) / 256, 256, 0, stream>>>(rowptr, deg, esrc, g, b2, out, N);
}